// Round 1
// baseline (972.773 us; speedup 1.0000x reference)
//
#include <hip/hip_runtime.h>
#include <math.h>

#define CC 64

__device__ __forceinline__ float silu_f(float v) {
    return v / (1.0f + __expf(-v));
}

// ---------------- K0: x = node_feats @ W_up  [N,64] @ [64,64] ----------------
__global__ void k_up(const float* __restrict__ nf, const float* __restrict__ Wup,
                     float* __restrict__ x, int N) {
    int tid = blockIdx.x * blockDim.x + threadIdx.x;
    if (tid >= N * CC) return;
    int n = tid >> 6;
    int j = tid & 63;
    const float* nfr = nf + (size_t)n * CC;   // n uniform per wave -> s_load
    float acc = 0.f;
#pragma unroll
    for (int k = 0; k < CC; ++k) acc += nfr[k] * Wup[k * CC + j];
    x[tid] = acc;
}

// ---------------- K1: radial MLP per edge -> mix [E,4,64] ----------------
// thread = edge. Activations live in a private LDS row (stride 65 -> bank
// (lane+k)%32, 2-way aliasing = free). k-loop runtime (small code), j
// unrolled with 64 register accumulators. Weight indices are wave-uniform
// -> scalar loads, ~98KB per 64 edges from K$/L2.
__global__ __launch_bounds__(128) void k_mlp(const float* __restrict__ rad,
        const float* __restrict__ w1, const float* __restrict__ w2,
        const float* __restrict__ w3, const float* __restrict__ w4,
        float* __restrict__ mixb, int e0, int ecount) {
    __shared__ float hbuf[128 * 65];
    int eloc = blockIdx.x * 128 + threadIdx.x;
    bool valid = (eloc < ecount);
    int e = e0 + (valid ? eloc : 0);
    float* hme = &hbuf[threadIdx.x * 65];

    // layer 1: 8 -> 64
    float r[8];
#pragma unroll
    for (int k = 0; k < 8; ++k) r[k] = rad[(size_t)e * 8 + k];
    float a[64];
#pragma unroll
    for (int j = 0; j < 64; ++j) a[j] = 0.f;
#pragma unroll
    for (int k = 0; k < 8; ++k) {
        float rv = r[k];
#pragma unroll
        for (int j = 0; j < 64; ++j) a[j] += rv * w1[k * 64 + j];
    }
#pragma unroll
    for (int j = 0; j < 64; ++j) hme[j] = silu_f(a[j]);

    // layer 2: 64 -> 64
#pragma unroll
    for (int j = 0; j < 64; ++j) a[j] = 0.f;
#pragma unroll 1
    for (int k = 0; k < 64; ++k) {
        float hv = hme[k];
#pragma unroll
        for (int j = 0; j < 64; ++j) a[j] += hv * w2[k * 64 + j];
    }
#pragma unroll
    for (int j = 0; j < 64; ++j) hme[j] = silu_f(a[j]);

    // layer 3: 64 -> 64
#pragma unroll
    for (int j = 0; j < 64; ++j) a[j] = 0.f;
#pragma unroll 1
    for (int k = 0; k < 64; ++k) {
        float hv = hme[k];
#pragma unroll
        for (int j = 0; j < 64; ++j) a[j] += hv * w3[k * 64 + j];
    }
#pragma unroll
    for (int j = 0; j < 64; ++j) hme[j] = silu_f(a[j]);

    // layer 4: 64 -> 256, processed as 4 chunks of 64 (one per irrep l)
#pragma unroll 1
    for (int l = 0; l < 4; ++l) {
#pragma unroll
        for (int j = 0; j < 64; ++j) a[j] = 0.f;
#pragma unroll 1
        for (int k = 0; k < 64; ++k) {
            float hv = hme[k];
#pragma unroll
            for (int j = 0; j < 64; ++j) a[j] += hv * w4[k * 256 + l * 64 + j];
        }
        if (valid) {
            float* mo = mixb + (size_t)eloc * 256 + l * 64;
#pragma unroll
            for (int j = 0; j < 64; ++j) mo[j] = a[j];
        }
    }
}

// ---------------- K2: per-edge messages + atomic segment-sum ----------------
// wave = edge, lane = channel. 16 atomics per lane -> contiguous 256B
// wave-regions in acc[n][16][64]. Fire-and-forget fp32 atomics.
__global__ void k_scatter(const float* __restrict__ x, const float* __restrict__ mixb,
        const float* __restrict__ vec, const int* __restrict__ snd,
        const int* __restrict__ rcv, float* __restrict__ acc, int e0, int ecount) {
    int wv = (int)((blockIdx.x * (size_t)blockDim.x + threadIdx.x) >> 6);
    int lane = threadIdx.x & 63;
    if (wv >= ecount) return;
    int e = e0 + wv;

    int s = snd[e];
    int rnode = rcv[e];

    float vx = vec[(size_t)e * 3 + 0];
    float vy = vec[(size_t)e * 3 + 1];
    float vz = vec[(size_t)e * 3 + 2];
    float nrm = sqrtf(vx * vx + vy * vy + vz * vz) + 1e-12f;
    float rinv = 1.0f / nrm;
    float ux = vx * rinv, uy = vy * rinv, uz = vz * rinv;

    const float s3 = 1.7320508075688772f;
    const float s5 = 2.2360679774997896f;
    const float s15 = 3.8729833462074170f;
    const float c1 = 2.0916500663351889f;   // sqrt(35/8)
    const float c2 = 10.246950765959598f;   // sqrt(105)
    const float c3 = 1.6201851746019651f;   // sqrt(21/8)
    const float c4 = 1.3228756555322954f;   // sqrt(7)/2

    float y10 = s3 * ux, y11 = s3 * uy, y12 = s3 * uz;
    float zz = uz * uz, xx = ux * ux, yy = uy * uy;
    float y20 = s15 * ux * uy;
    float y21 = s15 * uy * uz;
    float y22 = 0.5f * s5 * (3.f * zz - 1.f);
    float y23 = s15 * ux * uz;
    float y24 = 0.5f * s15 * (xx - yy);
    float y30 = c1 * uy * (3.f * xx - yy);
    float y31 = c2 * ux * uy * uz;
    float y32 = c3 * uy * (5.f * zz - 1.f);
    float y33 = c4 * uz * (5.f * zz - 3.f);
    float y34 = c3 * ux * (5.f * zz - 1.f);
    float y35 = 0.5f * c2 * uz * (xx - yy);
    float y36 = c1 * ux * (xx - yy);

    float sf = x[(size_t)s * 64 + lane];
    const float* mr = mixb + (size_t)wv * 256;
    float t0 = sf * mr[lane];
    float t1 = sf * mr[64 + lane];
    float t2 = sf * mr[128 + lane];
    float t3 = sf * mr[192 + lane];

    float* ar = acc + (size_t)rnode * 1024 + lane;
    atomicAdd(ar + 64 * 0, t0);
    atomicAdd(ar + 64 * 1, t1 * y10);
    atomicAdd(ar + 64 * 2, t1 * y11);
    atomicAdd(ar + 64 * 3, t1 * y12);
    atomicAdd(ar + 64 * 4, t2 * y20);
    atomicAdd(ar + 64 * 5, t2 * y21);
    atomicAdd(ar + 64 * 6, t2 * y22);
    atomicAdd(ar + 64 * 7, t2 * y23);
    atomicAdd(ar + 64 * 8, t2 * y24);
    atomicAdd(ar + 64 * 9, t3 * y30);
    atomicAdd(ar + 64 * 10, t3 * y31);
    atomicAdd(ar + 64 * 11, t3 * y32);
    atomicAdd(ar + 64 * 12, t3 * y33);
    atomicAdd(ar + 64 * 13, t3 * y34);
    atomicAdd(ar + 64 * 14, t3 * y35);
    atomicAdd(ar + 64 * 15, t3 * y36);
}

// ---------------- K3: per-node down-projection + output layout ----------------
// wave = node, lane = output channel d. acc row staged in LDS; W_down rows
// read coalesced (L2-hot, 64KB total). inv=0.25 folded into the store.
__global__ __launch_bounds__(256) void k_down(const float* __restrict__ acc,
        const float* __restrict__ Wd, float* __restrict__ out, int N) {
    __shared__ float sbuf[4][1024];
    int wv = threadIdx.x >> 6;
    int lane = threadIdx.x & 63;
    int n = blockIdx.x * 4 + wv;
    bool valid = (n < N);
    int nsafe = valid ? n : 0;
    const float* ar = acc + (size_t)nsafe * 1024;
#pragma unroll
    for (int t = 0; t < 16; ++t) sbuf[wv][t * 64 + lane] = ar[t * 64 + lane];
    __syncthreads();
    if (!valid) return;

    float o[16];
#pragma unroll
    for (int i = 0; i < 16; ++i) o[i] = 0.f;
#pragma unroll 1
    for (int c = 0; c < 64; ++c) {
        float w0 = Wd[c * 64 + lane];
        float w1r = Wd[4096 + c * 64 + lane];
        float w2r = Wd[8192 + c * 64 + lane];
        float w3r = Wd[12288 + c * 64 + lane];
        const float* sb = &sbuf[wv][c];
        o[0] += sb[0] * w0;
#pragma unroll
        for (int m = 0; m < 3; ++m) o[1 + m] += sb[(1 + m) * 64] * w1r;
#pragma unroll
        for (int m = 0; m < 5; ++m) o[4 + m] += sb[(4 + m) * 64] * w2r;
#pragma unroll
        for (int m = 0; m < 7; ++m) o[9 + m] += sb[(9 + m) * 64] * w3r;
    }

    float* outr = out + (size_t)n * 1024;
    outr[lane] = 0.25f * o[0];
#pragma unroll
    for (int m = 0; m < 3; ++m) outr[64 + lane * 3 + m] = 0.25f * o[1 + m];
#pragma unroll
    for (int m = 0; m < 5; ++m) outr[256 + lane * 5 + m] = 0.25f * o[4 + m];
#pragma unroll
    for (int m = 0; m < 7; ++m) outr[576 + lane * 7 + m] = 0.25f * o[9 + m];
}

extern "C" void kernel_launch(void* const* d_in, const int* in_sizes, int n_in,
                              void* d_out, int out_size, void* d_ws, size_t ws_size,
                              hipStream_t stream) {
    const float* vectors    = (const float*)d_in[0];
    const float* node_feats = (const float*)d_in[1];
    const float* radial     = (const float*)d_in[2];
    const float* W_up       = (const float*)d_in[3];
    const float* w1         = (const float*)d_in[4];
    const float* w2         = (const float*)d_in[5];
    const float* w3         = (const float*)d_in[6];
    const float* w4         = (const float*)d_in[7];
    const float* Wd         = (const float*)d_in[8];
    const int*   snd        = (const int*)d_in[9];
    const int*   rcv        = (const int*)d_in[10];
    float* out = (float*)d_out;

    int E = in_sizes[9];
    int N = in_sizes[1] / CC;

    // workspace layout (floats): x [N*64] | acc [N*1024] | mix [chunk*256]
    float* ws = (float*)d_ws;
    float* x    = ws;
    float* acc  = ws + (size_t)N * 64;
    float* mixb = acc + (size_t)N * 1024;

    size_t used = (size_t)N * 64 + (size_t)N * 1024;
    size_t avail = ws_size / 4 > used ? ws_size / 4 - used : 0;
    int chunk = (int)(avail / 256);
    if (chunk > E) chunk = E;
    if (chunk < 1) chunk = 1;  // ws too small would be unrecoverable anyway

    hipMemsetAsync(acc, 0, (size_t)N * 1024 * sizeof(float), stream);
    k_up<<<(N * CC + 255) / 256, 256, 0, stream>>>(node_feats, W_up, x, N);

    for (int e0 = 0; e0 < E; e0 += chunk) {
        int ec = E - e0 < chunk ? E - e0 : chunk;
        k_mlp<<<(ec + 127) / 128, 128, 0, stream>>>(radial, w1, w2, w3, w4, mixb, e0, ec);
        int waves = ec;
        k_scatter<<<(waves * 64 + 255) / 256, 256, 0, stream>>>(x, mixb, vectors, snd, rcv, acc, e0, ec);
    }

    k_down<<<(N + 3) / 4, 256, 0, stream>>>(acc, Wd, out, N);
}

// Round 2
// 493.922 us; speedup vs baseline: 1.9695x; 1.9695x over previous
//
#include <hip/hip_runtime.h>
#include <math.h>

#define CC 64

__device__ __forceinline__ float silu_f(float v) {
    return v / (1.0f + __expf(-v));
}

// ---------------- K0: x = node_feats @ W_up  [N,64] @ [64,64] ----------------
__global__ void k_up(const float* __restrict__ nf, const float* __restrict__ Wup,
                     float* __restrict__ x, int N) {
    int tid = blockIdx.x * blockDim.x + threadIdx.x;
    if (tid >= N * CC) return;
    int n = tid >> 6;
    int j = tid & 63;
    const float* nfr = nf + (size_t)n * CC;   // n uniform per wave -> s_load
    float acc = 0.f;
#pragma unroll
    for (int k = 0; k < CC; ++k) acc += nfr[k] * Wup[k * CC + j];
    x[tid] = acc;
}

// ---------------- K1: radial MLP per edge -> mix [E,4,64] ----------------
__global__ __launch_bounds__(128) void k_mlp(const float* __restrict__ rad,
        const float* __restrict__ w1, const float* __restrict__ w2,
        const float* __restrict__ w3, const float* __restrict__ w4,
        float* __restrict__ mixb, int ecount) {
    __shared__ float hbuf[128 * 65];
    int eloc = blockIdx.x * 128 + threadIdx.x;
    bool valid = (eloc < ecount);
    int e = valid ? eloc : 0;
    float* hme = &hbuf[threadIdx.x * 65];

    // layer 1: 8 -> 64
    float r[8];
#pragma unroll
    for (int k = 0; k < 8; ++k) r[k] = rad[(size_t)e * 8 + k];
    float a[64];
#pragma unroll
    for (int j = 0; j < 64; ++j) a[j] = 0.f;
#pragma unroll
    for (int k = 0; k < 8; ++k) {
        float rv = r[k];
#pragma unroll
        for (int j = 0; j < 64; ++j) a[j] += rv * w1[k * 64 + j];
    }
#pragma unroll
    for (int j = 0; j < 64; ++j) hme[j] = silu_f(a[j]);

    // layer 2: 64 -> 64
#pragma unroll
    for (int j = 0; j < 64; ++j) a[j] = 0.f;
#pragma unroll 1
    for (int k = 0; k < 64; ++k) {
        float hv = hme[k];
#pragma unroll
        for (int j = 0; j < 64; ++j) a[j] += hv * w2[k * 64 + j];
    }
#pragma unroll
    for (int j = 0; j < 64; ++j) hme[j] = silu_f(a[j]);

    // layer 3: 64 -> 64
#pragma unroll
    for (int j = 0; j < 64; ++j) a[j] = 0.f;
#pragma unroll 1
    for (int k = 0; k < 64; ++k) {
        float hv = hme[k];
#pragma unroll
        for (int j = 0; j < 64; ++j) a[j] += hv * w3[k * 64 + j];
    }
#pragma unroll
    for (int j = 0; j < 64; ++j) hme[j] = silu_f(a[j]);

    // layer 4: 64 -> 256, processed as 4 chunks of 64 (one per irrep l)
#pragma unroll 1
    for (int l = 0; l < 4; ++l) {
#pragma unroll
        for (int j = 0; j < 64; ++j) a[j] = 0.f;
#pragma unroll 1
        for (int k = 0; k < 64; ++k) {
            float hv = hme[k];
#pragma unroll
            for (int j = 0; j < 64; ++j) a[j] += hv * w4[k * 256 + l * 64 + j];
        }
        if (valid) {
            float* mo = mixb + (size_t)eloc * 256 + l * 64;
#pragma unroll
            for (int j = 0; j < 64; ++j) mo[j] = a[j];
        }
    }
}

// ---------------- CSR build: histogram -> scan -> fill ----------------
__global__ void k_hist(const int* __restrict__ rcv, int* __restrict__ cnt, int E) {
    int e = blockIdx.x * blockDim.x + threadIdx.x;
    if (e < E) atomicAdd(&cnt[rcv[e]], 1);
}

// single-workgroup exclusive scan over N counts -> off[N+1] and cursor copy
__global__ __launch_bounds__(1024) void k_scan(const int* __restrict__ cnt,
        int* __restrict__ off, int* __restrict__ cur, int N) {
    __shared__ int buf[1024];
    __shared__ int s_carry;
    int t = threadIdx.x;
    if (t == 0) s_carry = 0;
    __syncthreads();
    for (int base = 0; base < N; base += 1024) {
        int i = base + t;
        int v = (i < N) ? cnt[i] : 0;
        buf[t] = v;
        __syncthreads();
        for (int d = 1; d < 1024; d <<= 1) {
            int add = (t >= d) ? buf[t - d] : 0;
            __syncthreads();
            buf[t] += add;
            __syncthreads();
        }
        int excl = buf[t] - v + s_carry;   // s_carry read before update barrier
        if (i < N) { off[i] = excl; cur[i] = excl; }
        __syncthreads();
        if (t == 1023) s_carry += buf[1023];
        __syncthreads();
    }
    if (t == 0) off[N] = s_carry;
}

__global__ void k_fill(const int* __restrict__ rcv, int* __restrict__ cur,
                       int* __restrict__ eid, int E) {
    int e = blockIdx.x * blockDim.x + threadIdx.x;
    if (e < E) {
        int p = atomicAdd(&cur[rcv[e]], 1);
        eid[p] = e;
    }
}

// ---------------- K2: per-node gather + message + fused down-proj ----------------
// wave = node, lane = channel. Walks the node's CSR edge list, accumulates the
// 16 irrep components in registers (no atomics), then transposes through LDS
// and applies the per-l channel mix (W_down) + output layout in the epilogue.
__global__ __launch_bounds__(256) void k_gather(const float* __restrict__ x,
        const float* __restrict__ mixb, const float* __restrict__ vec,
        const int* __restrict__ snd, const int* __restrict__ eid,
        const int* __restrict__ off, const float* __restrict__ Wd,
        float* __restrict__ out, int N) {
    __shared__ float sbuf[4][1024];
    int wv = threadIdx.x >> 6;
    int lane = threadIdx.x & 63;
    int n = blockIdx.x * 4 + wv;
    if (n >= N) return;

    const float s3 = 1.7320508075688772f;
    const float s5 = 2.2360679774997896f;
    const float s15 = 3.8729833462074170f;
    const float c1 = 2.0916500663351889f;   // sqrt(35/8)
    const float c2 = 10.246950765959598f;   // sqrt(105)
    const float c3 = 1.6201851746019651f;   // sqrt(21/8)
    const float c4 = 1.3228756555322954f;   // sqrt(7)/2

    float o[16];
#pragma unroll
    for (int i = 0; i < 16; ++i) o[i] = 0.f;

    int beg = off[n], end = off[n + 1];
    for (int i = beg; i < end; ++i) {
        int e = eid[i];
        int s = snd[e];
        float vx = vec[(size_t)e * 3 + 0];
        float vy = vec[(size_t)e * 3 + 1];
        float vz = vec[(size_t)e * 3 + 2];
        float nrm = sqrtf(vx * vx + vy * vy + vz * vz) + 1e-12f;
        float rinv = 1.0f / nrm;
        float ux = vx * rinv, uy = vy * rinv, uz = vz * rinv;

        float zz = uz * uz, xx = ux * ux, yy = uy * uy;
        float y10 = s3 * ux, y11 = s3 * uy, y12 = s3 * uz;
        float y20 = s15 * ux * uy;
        float y21 = s15 * uy * uz;
        float y22 = 0.5f * s5 * (3.f * zz - 1.f);
        float y23 = s15 * ux * uz;
        float y24 = 0.5f * s15 * (xx - yy);
        float y30 = c1 * uy * (3.f * xx - yy);
        float y31 = c2 * ux * uy * uz;
        float y32 = c3 * uy * (5.f * zz - 1.f);
        float y33 = c4 * uz * (5.f * zz - 3.f);
        float y34 = c3 * ux * (5.f * zz - 1.f);
        float y35 = 0.5f * c2 * uz * (xx - yy);
        float y36 = c1 * ux * (xx - yy);

        float sf = x[(size_t)s * 64 + lane];
        const float* mr = mixb + (size_t)e * 256;
        float t0 = sf * mr[lane];
        float t1 = sf * mr[64 + lane];
        float t2 = sf * mr[128 + lane];
        float t3 = sf * mr[192 + lane];

        o[0]  += t0;
        o[1]  += t1 * y10;
        o[2]  += t1 * y11;
        o[3]  += t1 * y12;
        o[4]  += t2 * y20;
        o[5]  += t2 * y21;
        o[6]  += t2 * y22;
        o[7]  += t2 * y23;
        o[8]  += t2 * y24;
        o[9]  += t3 * y30;
        o[10] += t3 * y31;
        o[11] += t3 * y32;
        o[12] += t3 * y33;
        o[13] += t3 * y34;
        o[14] += t3 * y35;
        o[15] += t3 * y36;
    }

    // register -> LDS transpose (wave-private region, no barrier needed)
#pragma unroll
    for (int t = 0; t < 16; ++t) sbuf[wv][t * 64 + lane] = o[t];

    // down-projection: lane = output channel d
    float d[16];
#pragma unroll
    for (int i = 0; i < 16; ++i) d[i] = 0.f;
#pragma unroll 1
    for (int c = 0; c < 64; ++c) {
        float w0 = Wd[c * 64 + lane];
        float w1r = Wd[4096 + c * 64 + lane];
        float w2r = Wd[8192 + c * 64 + lane];
        float w3r = Wd[12288 + c * 64 + lane];
        const float* sb = &sbuf[wv][c];
        d[0] += sb[0] * w0;
#pragma unroll
        for (int m = 0; m < 3; ++m) d[1 + m] += sb[(1 + m) * 64] * w1r;
#pragma unroll
        for (int m = 0; m < 5; ++m) d[4 + m] += sb[(4 + m) * 64] * w2r;
#pragma unroll
        for (int m = 0; m < 7; ++m) d[9 + m] += sb[(9 + m) * 64] * w3r;
    }

    float* outr = out + (size_t)n * 1024;
    outr[lane] = 0.25f * d[0];
#pragma unroll
    for (int m = 0; m < 3; ++m) outr[64 + lane * 3 + m] = 0.25f * d[1 + m];
#pragma unroll
    for (int m = 0; m < 5; ++m) outr[256 + lane * 5 + m] = 0.25f * d[4 + m];
#pragma unroll
    for (int m = 0; m < 7; ++m) outr[576 + lane * 7 + m] = 0.25f * d[9 + m];
}

extern "C" void kernel_launch(void* const* d_in, const int* in_sizes, int n_in,
                              void* d_out, int out_size, void* d_ws, size_t ws_size,
                              hipStream_t stream) {
    const float* vectors    = (const float*)d_in[0];
    const float* node_feats = (const float*)d_in[1];
    const float* radial     = (const float*)d_in[2];
    const float* w1         = (const float*)d_in[4];
    const float* w2         = (const float*)d_in[5];
    const float* w3         = (const float*)d_in[6];
    const float* w4         = (const float*)d_in[7];
    const float* W_up       = (const float*)d_in[3];
    const float* Wd         = (const float*)d_in[8];
    const int*   snd        = (const int*)d_in[9];
    const int*   rcv        = (const int*)d_in[10];
    float* out = (float*)d_out;

    int E = in_sizes[9];
    int N = in_sizes[1] / CC;

    // workspace layout: x [N*64]f | mix [E*256]f | cnt [N]i | off [N+1]i | cur [N]i | eid [E]i
    float* ws   = (float*)d_ws;
    float* x    = ws;
    float* mixb = x + (size_t)N * 64;
    int*   cnt  = (int*)(mixb + (size_t)E * 256);
    int*   off  = cnt + N;
    int*   cur  = off + (N + 1);
    int*   eid  = cur + N;

    hipMemsetAsync(cnt, 0, (size_t)N * sizeof(int), stream);

    k_up<<<(N * CC + 255) / 256, 256, 0, stream>>>(node_feats, W_up, x, N);
    k_hist<<<(E + 255) / 256, 256, 0, stream>>>(rcv, cnt, E);
    k_scan<<<1, 1024, 0, stream>>>(cnt, off, cur, N);
    k_fill<<<(E + 255) / 256, 256, 0, stream>>>(rcv, cur, eid, E);
    k_mlp<<<(E + 127) / 128, 128, 0, stream>>>(radial, w1, w2, w3, w4, mixb, E);
    k_gather<<<(N + 3) / 4, 256, 0, stream>>>(x, mixb, vectors, snd, eid, off, Wd, out, N);
}

// Round 3
// 267.210 us; speedup vs baseline: 3.6405x; 1.8484x over previous
//
#include <hip/hip_runtime.h>
#include <math.h>

#define CC 64
typedef _Float16 f16;
typedef _Float16 half8_t __attribute__((ext_vector_type(8)));
typedef float f32x4 __attribute__((ext_vector_type(4)));

__device__ __forceinline__ float silu_f(float v) {
    return v / (1.0f + __expf(-v));
}

// ---------------- K0: x = node_feats @ W_up  [N,64] @ [64,64] ----------------
__global__ void k_up(const float* __restrict__ nf, const float* __restrict__ Wup,
                     float* __restrict__ x, int N) {
    int tid = blockIdx.x * blockDim.x + threadIdx.x;
    if (tid >= N * CC) return;
    int n = tid >> 6;
    int j = tid & 63;
    const float* nfr = nf + (size_t)n * CC;   // n uniform per wave -> s_load
    float acc = 0.f;
#pragma unroll
    for (int k = 0; k < CC; ++k) acc += nfr[k] * Wup[k * CC + j];
    x[tid] = acc;
}

// ---------------- K1: radial MLP via fp16 MFMA -> mix [E,256] fp16 ----------------
// block = 128 edges, 4 waves x 32 rows (2 m-tiles of 16). Layer 1 (K=8) in
// VALU during staging; layers 2-4 as mfma_f32_16x16x32_f16. Weights staged
// transposed (wT[n][k], stride 72 halfs = 144B, 16B-aligned, bank-balanced).
// w4 reuses the w2/w3 LDS buffers in two chunk-phases. LDS 36KB -> 4 blk/CU.
__global__ __launch_bounds__(256) void k_mlp(const float* __restrict__ rad,
        const float* __restrict__ w1, const float* __restrict__ w2,
        const float* __restrict__ w3, const float* __restrict__ w4,
        f16* __restrict__ mixb, int E) {
    __shared__ f16 wB[64][72];
    __shared__ f16 wC[64][72];
    __shared__ f16 act[128][72];

    int t = threadIdx.x;
    int e0 = blockIdx.x * 128;
    int lane = t & 63;
    int wid = t >> 6;

    // ---- stage w2 -> wB, w3 -> wC (transposed, fp16) ----
    {
        int n = t & 63;
        int k0 = t >> 6;
        for (int k = k0; k < 64; k += 4) {
            wB[n][k] = (f16)w2[k * 64 + n];
            wC[n][k] = (f16)w3[k * 64 + n];
        }
    }

    // ---- layer 1 in VALU: act[i][j] = silu(sum_k rad[e0+i][k] * w1[k][j]) ----
    {
        int i = t & 127;
        int jh = (t >> 7) * 32;           // wave-uniform -> w1 reads are s_load
        int e = e0 + i;
        float r[8];
        if (e < E) {
#pragma unroll
            for (int k = 0; k < 8; ++k) r[k] = rad[(size_t)e * 8 + k];
        } else {
#pragma unroll
            for (int k = 0; k < 8; ++k) r[k] = 0.f;
        }
        float a[32];
#pragma unroll
        for (int j = 0; j < 32; ++j) a[j] = 0.f;
#pragma unroll
        for (int k = 0; k < 8; ++k) {
            float rv = r[k];
#pragma unroll
            for (int j = 0; j < 32; ++j) a[j] += rv * w1[k * 64 + jh + j];
        }
#pragma unroll
        for (int jj = 0; jj < 32; jj += 8) {
            half8_t h;
#pragma unroll
            for (int u = 0; u < 8; ++u) h[u] = (f16)silu_f(a[jj + u]);
            *(half8_t*)&act[i][jh + jj] = h;
        }
    }
    __syncthreads();

    // wave owns rows [wid*32, wid*32+32) of act -> no barriers between layers
    int m0 = wid * 32;
    int fm = lane & 15;
    int q  = lane >> 4;

    auto loadA = [&](int mbase, int kc) -> half8_t {
        return *(const half8_t*)&act[mbase + fm][kc + q * 8];
    };

    // ---- layer 2 (weights wB) ----
    {
        half8_t a00 = loadA(m0, 0),      a01 = loadA(m0, 32);
        half8_t a10 = loadA(m0 + 16, 0), a11 = loadA(m0 + 16, 32);
#pragma unroll
        for (int nt = 0; nt < 4; ++nt) {
            half8_t b0 = *(const half8_t*)&wB[nt * 16 + fm][q * 8];
            half8_t b1 = *(const half8_t*)&wB[nt * 16 + fm][32 + q * 8];
            f32x4 c0 = {0.f, 0.f, 0.f, 0.f};
            c0 = __builtin_amdgcn_mfma_f32_16x16x32_f16(a00, b0, c0, 0, 0, 0);
            c0 = __builtin_amdgcn_mfma_f32_16x16x32_f16(a01, b1, c0, 0, 0, 0);
            f32x4 c1 = {0.f, 0.f, 0.f, 0.f};
            c1 = __builtin_amdgcn_mfma_f32_16x16x32_f16(a10, b0, c1, 0, 0, 0);
            c1 = __builtin_amdgcn_mfma_f32_16x16x32_f16(a11, b1, c1, 0, 0, 0);
#pragma unroll
            for (int r = 0; r < 4; ++r) {
                act[m0 + q * 4 + r][nt * 16 + fm]      = (f16)silu_f(c0[r]);
                act[m0 + 16 + q * 4 + r][nt * 16 + fm] = (f16)silu_f(c1[r]);
            }
        }
    }

    // ---- layer 3 (weights wC) ----
    {
        half8_t a00 = loadA(m0, 0),      a01 = loadA(m0, 32);
        half8_t a10 = loadA(m0 + 16, 0), a11 = loadA(m0 + 16, 32);
#pragma unroll
        for (int nt = 0; nt < 4; ++nt) {
            half8_t b0 = *(const half8_t*)&wC[nt * 16 + fm][q * 8];
            half8_t b1 = *(const half8_t*)&wC[nt * 16 + fm][32 + q * 8];
            f32x4 c0 = {0.f, 0.f, 0.f, 0.f};
            c0 = __builtin_amdgcn_mfma_f32_16x16x32_f16(a00, b0, c0, 0, 0, 0);
            c0 = __builtin_amdgcn_mfma_f32_16x16x32_f16(a01, b1, c0, 0, 0, 0);
            f32x4 c1 = {0.f, 0.f, 0.f, 0.f};
            c1 = __builtin_amdgcn_mfma_f32_16x16x32_f16(a10, b0, c1, 0, 0, 0);
            c1 = __builtin_amdgcn_mfma_f32_16x16x32_f16(a11, b1, c1, 0, 0, 0);
#pragma unroll
            for (int r = 0; r < 4; ++r) {
                act[m0 + q * 4 + r][nt * 16 + fm]      = (f16)silu_f(c0[r]);
                act[m0 + 16 + q * 4 + r][nt * 16 + fm] = (f16)silu_f(c1[r]);
            }
        }
    }

    // ---- layer 4: A-frags (X3) into regs, then w4 in 2 LDS chunk-phases ----
    half8_t A00 = loadA(m0, 0),      A01 = loadA(m0, 32);
    half8_t A10 = loadA(m0 + 16, 0), A11 = loadA(m0 + 16, 32);

    auto do_l = [&](int l, f16 (*w)[72]) {
#pragma unroll
        for (int nt = 0; nt < 4; ++nt) {
            half8_t b0 = *(const half8_t*)&w[nt * 16 + fm][q * 8];
            half8_t b1 = *(const half8_t*)&w[nt * 16 + fm][32 + q * 8];
            f32x4 c0 = {0.f, 0.f, 0.f, 0.f};
            c0 = __builtin_amdgcn_mfma_f32_16x16x32_f16(A00, b0, c0, 0, 0, 0);
            c0 = __builtin_amdgcn_mfma_f32_16x16x32_f16(A01, b1, c0, 0, 0, 0);
            f32x4 c1 = {0.f, 0.f, 0.f, 0.f};
            c1 = __builtin_amdgcn_mfma_f32_16x16x32_f16(A10, b0, c1, 0, 0, 0);
            c1 = __builtin_amdgcn_mfma_f32_16x16x32_f16(A11, b1, c1, 0, 0, 0);
            int col = l * 64 + nt * 16 + fm;
#pragma unroll
            for (int r = 0; r < 4; ++r) {
                int er0 = e0 + m0 + q * 4 + r;
                int er1 = er0 + 16;
                if (er0 < E) mixb[(size_t)er0 * 256 + col] = (f16)c0[r];
                if (er1 < E) mixb[(size_t)er1 * 256 + col] = (f16)c1[r];
            }
        }
    };

    __syncthreads();   // everyone done reading wB/wC
    {
        int n = t & 63;
        int k0 = t >> 6;
        for (int k = k0; k < 64; k += 4) {
            wB[n][k] = (f16)w4[k * 256 + n];           // l=0
            wC[n][k] = (f16)w4[k * 256 + 64 + n];      // l=1
        }
    }
    __syncthreads();
    do_l(0, wB);
    do_l(1, wC);
    __syncthreads();
    {
        int n = t & 63;
        int k0 = t >> 6;
        for (int k = k0; k < 64; k += 4) {
            wB[n][k] = (f16)w4[k * 256 + 128 + n];     // l=2
            wC[n][k] = (f16)w4[k * 256 + 192 + n];     // l=3
        }
    }
    __syncthreads();
    do_l(2, wB);
    do_l(3, wC);
}

// ---------------- CSR build: histogram -> scan -> fill ----------------
__global__ void k_hist(const int* __restrict__ rcv, int* __restrict__ cnt, int E) {
    int e = blockIdx.x * blockDim.x + threadIdx.x;
    if (e < E) atomicAdd(&cnt[rcv[e]], 1);
}

__global__ __launch_bounds__(1024) void k_scan(const int* __restrict__ cnt,
        int* __restrict__ off, int* __restrict__ cur, int N) {
    __shared__ int buf[1024];
    __shared__ int s_carry;
    int t = threadIdx.x;
    if (t == 0) s_carry = 0;
    __syncthreads();
    for (int base = 0; base < N; base += 1024) {
        int i = base + t;
        int v = (i < N) ? cnt[i] : 0;
        buf[t] = v;
        __syncthreads();
        for (int d = 1; d < 1024; d <<= 1) {
            int add = (t >= d) ? buf[t - d] : 0;
            __syncthreads();
            buf[t] += add;
            __syncthreads();
        }
        int excl = buf[t] - v + s_carry;
        if (i < N) { off[i] = excl; cur[i] = excl; }
        __syncthreads();
        if (t == 1023) s_carry += buf[1023];
        __syncthreads();
    }
    if (t == 0) off[N] = s_carry;
}

__global__ void k_fill(const int* __restrict__ rcv, int* __restrict__ cur,
                       int* __restrict__ eid, int E) {
    int e = blockIdx.x * blockDim.x + threadIdx.x;
    if (e < E) {
        int p = atomicAdd(&cur[rcv[e]], 1);
        eid[p] = e;
    }
}

// ---------------- K2: per-node gather + message + fused down-proj ----------------
__global__ __launch_bounds__(256) void k_gather(const float* __restrict__ x,
        const f16* __restrict__ mixb, const float* __restrict__ vec,
        const int* __restrict__ snd, const int* __restrict__ eid,
        const int* __restrict__ off, const float* __restrict__ Wd,
        float* __restrict__ out, int N) {
    __shared__ float sbuf[4][1024];
    int wv = threadIdx.x >> 6;
    int lane = threadIdx.x & 63;
    int n = blockIdx.x * 4 + wv;
    if (n >= N) return;

    const float s3 = 1.7320508075688772f;
    const float s5 = 2.2360679774997896f;
    const float s15 = 3.8729833462074170f;
    const float c1 = 2.0916500663351889f;
    const float c2 = 10.246950765959598f;
    const float c3 = 1.6201851746019651f;
    const float c4 = 1.3228756555322954f;

    float o[16];
#pragma unroll
    for (int i = 0; i < 16; ++i) o[i] = 0.f;

    int beg = off[n], end = off[n + 1];
    for (int i = beg; i < end; ++i) {
        int e = eid[i];
        int s = snd[e];
        float vx = vec[(size_t)e * 3 + 0];
        float vy = vec[(size_t)e * 3 + 1];
        float vz = vec[(size_t)e * 3 + 2];
        float nrm = sqrtf(vx * vx + vy * vy + vz * vz) + 1e-12f;
        float rinv = 1.0f / nrm;
        float ux = vx * rinv, uy = vy * rinv, uz = vz * rinv;

        float zz = uz * uz, xx = ux * ux, yy = uy * uy;
        float y10 = s3 * ux, y11 = s3 * uy, y12 = s3 * uz;
        float y20 = s15 * ux * uy;
        float y21 = s15 * uy * uz;
        float y22 = 0.5f * s5 * (3.f * zz - 1.f);
        float y23 = s15 * ux * uz;
        float y24 = 0.5f * s15 * (xx - yy);
        float y30 = c1 * uy * (3.f * xx - yy);
        float y31 = c2 * ux * uy * uz;
        float y32 = c3 * uy * (5.f * zz - 1.f);
        float y33 = c4 * uz * (5.f * zz - 3.f);
        float y34 = c3 * ux * (5.f * zz - 1.f);
        float y35 = 0.5f * c2 * uz * (xx - yy);
        float y36 = c1 * ux * (xx - yy);

        float sf = x[(size_t)s * 64 + lane];
        const f16* mr = mixb + (size_t)e * 256;
        float t0 = sf * (float)mr[lane];
        float t1 = sf * (float)mr[64 + lane];
        float t2 = sf * (float)mr[128 + lane];
        float t3 = sf * (float)mr[192 + lane];

        o[0]  += t0;
        o[1]  += t1 * y10;
        o[2]  += t1 * y11;
        o[3]  += t1 * y12;
        o[4]  += t2 * y20;
        o[5]  += t2 * y21;
        o[6]  += t2 * y22;
        o[7]  += t2 * y23;
        o[8]  += t2 * y24;
        o[9]  += t3 * y30;
        o[10] += t3 * y31;
        o[11] += t3 * y32;
        o[12] += t3 * y33;
        o[13] += t3 * y34;
        o[14] += t3 * y35;
        o[15] += t3 * y36;
    }

    // register -> LDS transpose (wave-private region, no barrier needed)
#pragma unroll
    for (int t = 0; t < 16; ++t) sbuf[wv][t * 64 + lane] = o[t];

    float d[16];
#pragma unroll
    for (int i = 0; i < 16; ++i) d[i] = 0.f;
#pragma unroll 1
    for (int c = 0; c < 64; ++c) {
        float w0 = Wd[c * 64 + lane];
        float w1r = Wd[4096 + c * 64 + lane];
        float w2r = Wd[8192 + c * 64 + lane];
        float w3r = Wd[12288 + c * 64 + lane];
        const float* sb = &sbuf[wv][c];
        d[0] += sb[0] * w0;
#pragma unroll
        for (int m = 0; m < 3; ++m) d[1 + m] += sb[(1 + m) * 64] * w1r;
#pragma unroll
        for (int m = 0; m < 5; ++m) d[4 + m] += sb[(4 + m) * 64] * w2r;
#pragma unroll
        for (int m = 0; m < 7; ++m) d[9 + m] += sb[(9 + m) * 64] * w3r;
    }

    float* outr = out + (size_t)n * 1024;
    outr[lane] = 0.25f * d[0];
#pragma unroll
    for (int m = 0; m < 3; ++m) outr[64 + lane * 3 + m] = 0.25f * d[1 + m];
#pragma unroll
    for (int m = 0; m < 5; ++m) outr[256 + lane * 5 + m] = 0.25f * d[4 + m];
#pragma unroll
    for (int m = 0; m < 7; ++m) outr[576 + lane * 7 + m] = 0.25f * d[9 + m];
}

extern "C" void kernel_launch(void* const* d_in, const int* in_sizes, int n_in,
                              void* d_out, int out_size, void* d_ws, size_t ws_size,
                              hipStream_t stream) {
    const float* vectors    = (const float*)d_in[0];
    const float* node_feats = (const float*)d_in[1];
    const float* radial     = (const float*)d_in[2];
    const float* W_up       = (const float*)d_in[3];
    const float* w1         = (const float*)d_in[4];
    const float* w2         = (const float*)d_in[5];
    const float* w3         = (const float*)d_in[6];
    const float* w4         = (const float*)d_in[7];
    const float* Wd         = (const float*)d_in[8];
    const int*   snd        = (const int*)d_in[9];
    const int*   rcv        = (const int*)d_in[10];
    float* out = (float*)d_out;

    int E = in_sizes[9];
    int N = in_sizes[1] / CC;

    // ws layout: x [N*64]f | mix [E*256]f16 | cnt [N]i | off [N+1]i | cur [N]i | eid [E]i
    float* ws   = (float*)d_ws;
    float* x    = ws;
    f16*   mixb = (f16*)(x + (size_t)N * 64);
    int*   cnt  = (int*)((char*)mixb + (size_t)E * 256 * sizeof(f16));
    int*   off  = cnt + N;
    int*   cur  = off + (N + 1);
    int*   eid  = cur + N;

    hipMemsetAsync(cnt, 0, (size_t)N * sizeof(int), stream);

    k_up<<<(N * CC + 255) / 256, 256, 0, stream>>>(node_feats, W_up, x, N);
    k_hist<<<(E + 255) / 256, 256, 0, stream>>>(rcv, cnt, E);
    k_scan<<<1, 1024, 0, stream>>>(cnt, off, cur, N);
    k_fill<<<(E + 255) / 256, 256, 0, stream>>>(rcv, cur, eid, E);
    k_mlp<<<(E + 127) / 128, 256, 0, stream>>>(radial, w1, w2, w3, w4, mixb, E);
    k_gather<<<(N + 3) / 4, 256, 0, stream>>>(x, mixb, vectors, snd, eid, off, Wd, out, N);
}

// Round 4
// 253.662 us; speedup vs baseline: 3.8349x; 1.0534x over previous
//
#include <hip/hip_runtime.h>
#include <math.h>

#define CC 64
typedef _Float16 f16;
typedef _Float16 half8_t __attribute__((ext_vector_type(8)));
typedef float f32x4 __attribute__((ext_vector_type(4)));

__device__ __forceinline__ float silu_f(float v) {
    return v / (1.0f + __expf(-v));
}

// ---------------- K0: x = node_feats @ W_up  [N,64] @ [64,64] ----------------
__global__ void k_up(const float* __restrict__ nf, const float* __restrict__ Wup,
                     float* __restrict__ x, int N) {
    int tid = blockIdx.x * blockDim.x + threadIdx.x;
    if (tid >= N * CC) return;
    int n = tid >> 6;
    int j = tid & 63;
    const float* nfr = nf + (size_t)n * CC;
    float acc = 0.f;
#pragma unroll
    for (int k = 0; k < CC; ++k) acc += nfr[k] * Wup[k * CC + j];
    x[tid] = acc;
}

// ---------------- CSR build: histogram -> scan -> fill ----------------
__global__ void k_hist(const int* __restrict__ rcv, int* __restrict__ cnt, int E) {
    int e = blockIdx.x * blockDim.x + threadIdx.x;
    if (e < E) atomicAdd(&cnt[rcv[e]], 1);
}

// shfl-based exclusive scan, single workgroup of 1024
__global__ __launch_bounds__(1024) void k_scan(const int* __restrict__ cnt,
        int* __restrict__ off, int* __restrict__ cur, int N) {
    __shared__ int wsum[16];
    __shared__ int carry;
    int t = threadIdx.x;
    int wave = t >> 6, lane = t & 63;
    if (t == 0) carry = 0;
    __syncthreads();
    for (int base = 0; base < N; base += 1024) {
        int i = base + t;
        int v = (i < N) ? cnt[i] : 0;
        int sc = v;
#pragma unroll
        for (int d = 1; d < 64; d <<= 1) {
            int u = __shfl_up(sc, d, 64);
            if (lane >= d) sc += u;
        }
        if (lane == 63) wsum[wave] = sc;
        __syncthreads();
        if (wave == 0) {
            int w = (lane < 16) ? wsum[lane] : 0;
            int s2 = w;
#pragma unroll
            for (int d = 1; d < 16; d <<= 1) {
                int u = __shfl_up(s2, d, 64);
                if (lane >= d) s2 += u;
            }
            if (lane < 16) wsum[lane] = s2;
        }
        __syncthreads();
        int wexcl = (wave == 0) ? 0 : wsum[wave - 1];
        int excl = carry + wexcl + (sc - v);
        if (i < N) { off[i] = excl; cur[i] = excl; }
        __syncthreads();
        if (t == 0) carry += wsum[15];
        __syncthreads();
    }
    if (t == 0) off[N] = carry;
}

__global__ void k_fill(const int* __restrict__ rcv, const int* __restrict__ snd,
                       int* __restrict__ cur, int* __restrict__ eid,
                       int* __restrict__ pos, int* __restrict__ sndp, int E) {
    int e = blockIdx.x * blockDim.x + threadIdx.x;
    if (e < E) {
        int p = atomicAdd(&cur[rcv[e]], 1);
        eid[p] = e;
        pos[e] = p;
        sndp[p] = snd[e];
    }
}

// ---------------- K_sph: spherical harmonics per edge, CSR order ----------------
// yb[i][16] = {1, y1(3), y2(5), y3(7)} for edge eid[i]
__global__ void k_sph(const int* __restrict__ eid, const float* __restrict__ vec,
                      float* __restrict__ yb, int E) {
    int i = blockIdx.x * blockDim.x + threadIdx.x;
    if (i >= E) return;
    int e = eid[i];
    float vx = vec[(size_t)e * 3 + 0];
    float vy = vec[(size_t)e * 3 + 1];
    float vz = vec[(size_t)e * 3 + 2];
    float nrm = sqrtf(vx * vx + vy * vy + vz * vz) + 1e-12f;
    float rinv = 1.0f / nrm;
    float ux = vx * rinv, uy = vy * rinv, uz = vz * rinv;

    const float s3 = 1.7320508075688772f;
    const float s5 = 2.2360679774997896f;
    const float s15 = 3.8729833462074170f;
    const float c1 = 2.0916500663351889f;
    const float c2 = 10.246950765959598f;
    const float c3 = 1.6201851746019651f;
    const float c4 = 1.3228756555322954f;

    float zz = uz * uz, xx = ux * ux, yy = uy * uy;
    float4 r0 = {1.0f, s3 * ux, s3 * uy, s3 * uz};
    float4 r1 = {s15 * ux * uy, s15 * uy * uz, 0.5f * s5 * (3.f * zz - 1.f),
                 s15 * ux * uz};
    float4 r2 = {0.5f * s15 * (xx - yy), c1 * uy * (3.f * xx - yy),
                 c2 * ux * uy * uz, c3 * uy * (5.f * zz - 1.f)};
    float4 r3 = {c4 * uz * (5.f * zz - 3.f), c3 * ux * (5.f * zz - 1.f),
                 0.5f * c2 * uz * (xx - yy), c1 * ux * (xx - yy)};
    float* yr = yb + (size_t)i * 16;
    *(float4*)(yr + 0)  = r0;
    *(float4*)(yr + 4)  = r1;
    *(float4*)(yr + 8)  = r2;
    *(float4*)(yr + 12) = r3;
}

// ---------------- K1: radial MLP via fp16 MFMA -> mixp [E,256] f16, CSR rows ----
__global__ __launch_bounds__(256) void k_mlp(const float* __restrict__ rad,
        const float* __restrict__ w1, const float* __restrict__ w2,
        const float* __restrict__ w3, const float* __restrict__ w4,
        const int* __restrict__ pos, f16* __restrict__ mixp, int E) {
    __shared__ f16 wB[64][72];
    __shared__ f16 wC[64][72];
    __shared__ f16 act[128][72];

    int t = threadIdx.x;
    int e0 = blockIdx.x * 128;
    int lane = t & 63;
    int wid = t >> 6;

    // stage w2 -> wB, w3 -> wC (transposed, fp16)
    {
        int n = t & 63;
        int k0 = t >> 6;
        for (int k = k0; k < 64; k += 4) {
            wB[n][k] = (f16)w2[k * 64 + n];
            wC[n][k] = (f16)w3[k * 64 + n];
        }
    }

    // layer 1 in VALU
    {
        int i = t & 127;
        int jh = (t >> 7) * 32;
        int e = e0 + i;
        float r[8];
        if (e < E) {
#pragma unroll
            for (int k = 0; k < 8; ++k) r[k] = rad[(size_t)e * 8 + k];
        } else {
#pragma unroll
            for (int k = 0; k < 8; ++k) r[k] = 0.f;
        }
        float a[32];
#pragma unroll
        for (int j = 0; j < 32; ++j) a[j] = 0.f;
#pragma unroll
        for (int k = 0; k < 8; ++k) {
            float rv = r[k];
#pragma unroll
            for (int j = 0; j < 32; ++j) a[j] += rv * w1[k * 64 + jh + j];
        }
#pragma unroll
        for (int jj = 0; jj < 32; jj += 8) {
            half8_t h;
#pragma unroll
            for (int u = 0; u < 8; ++u) h[u] = (f16)silu_f(a[jj + u]);
            *(half8_t*)&act[i][jh + jj] = h;
        }
    }
    __syncthreads();

    int m0 = wid * 32;
    int fm = lane & 15;
    int q  = lane >> 4;

    auto loadA = [&](int mbase, int kc) -> half8_t {
        return *(const half8_t*)&act[mbase + fm][kc + q * 8];
    };

    // layer 2
    {
        half8_t a00 = loadA(m0, 0),      a01 = loadA(m0, 32);
        half8_t a10 = loadA(m0 + 16, 0), a11 = loadA(m0 + 16, 32);
#pragma unroll
        for (int nt = 0; nt < 4; ++nt) {
            half8_t b0 = *(const half8_t*)&wB[nt * 16 + fm][q * 8];
            half8_t b1 = *(const half8_t*)&wB[nt * 16 + fm][32 + q * 8];
            f32x4 c0 = {0.f, 0.f, 0.f, 0.f};
            c0 = __builtin_amdgcn_mfma_f32_16x16x32_f16(a00, b0, c0, 0, 0, 0);
            c0 = __builtin_amdgcn_mfma_f32_16x16x32_f16(a01, b1, c0, 0, 0, 0);
            f32x4 c1 = {0.f, 0.f, 0.f, 0.f};
            c1 = __builtin_amdgcn_mfma_f32_16x16x32_f16(a10, b0, c1, 0, 0, 0);
            c1 = __builtin_amdgcn_mfma_f32_16x16x32_f16(a11, b1, c1, 0, 0, 0);
#pragma unroll
            for (int r = 0; r < 4; ++r) {
                act[m0 + q * 4 + r][nt * 16 + fm]      = (f16)silu_f(c0[r]);
                act[m0 + 16 + q * 4 + r][nt * 16 + fm] = (f16)silu_f(c1[r]);
            }
        }
    }

    // layer 3
    {
        half8_t a00 = loadA(m0, 0),      a01 = loadA(m0, 32);
        half8_t a10 = loadA(m0 + 16, 0), a11 = loadA(m0 + 16, 32);
#pragma unroll
        for (int nt = 0; nt < 4; ++nt) {
            half8_t b0 = *(const half8_t*)&wC[nt * 16 + fm][q * 8];
            half8_t b1 = *(const half8_t*)&wC[nt * 16 + fm][32 + q * 8];
            f32x4 c0 = {0.f, 0.f, 0.f, 0.f};
            c0 = __builtin_amdgcn_mfma_f32_16x16x32_f16(a00, b0, c0, 0, 0, 0);
            c0 = __builtin_amdgcn_mfma_f32_16x16x32_f16(a01, b1, c0, 0, 0, 0);
            f32x4 c1 = {0.f, 0.f, 0.f, 0.f};
            c1 = __builtin_amdgcn_mfma_f32_16x16x32_f16(a10, b0, c1, 0, 0, 0);
            c1 = __builtin_amdgcn_mfma_f32_16x16x32_f16(a11, b1, c1, 0, 0, 0);
#pragma unroll
            for (int r = 0; r < 4; ++r) {
                act[m0 + q * 4 + r][nt * 16 + fm]      = (f16)silu_f(c0[r]);
                act[m0 + 16 + q * 4 + r][nt * 16 + fm] = (f16)silu_f(c1[r]);
            }
        }
    }

    // layer 4: A-frags into regs, w4 in 2 LDS chunk-phases
    half8_t A00 = loadA(m0, 0),      A01 = loadA(m0, 32);
    half8_t A10 = loadA(m0 + 16, 0), A11 = loadA(m0 + 16, 32);

    // per-l: MFMA -> wave-private act reshuffle -> half8 global stores (rows
    // permuted to CSR order via pos)
    auto do_l = [&](int l, f16 (*w)[72]) {
#pragma unroll
        for (int nt = 0; nt < 4; ++nt) {
            half8_t b0 = *(const half8_t*)&w[nt * 16 + fm][q * 8];
            half8_t b1 = *(const half8_t*)&w[nt * 16 + fm][32 + q * 8];
            f32x4 c0 = {0.f, 0.f, 0.f, 0.f};
            c0 = __builtin_amdgcn_mfma_f32_16x16x32_f16(A00, b0, c0, 0, 0, 0);
            c0 = __builtin_amdgcn_mfma_f32_16x16x32_f16(A01, b1, c0, 0, 0, 0);
            f32x4 c1 = {0.f, 0.f, 0.f, 0.f};
            c1 = __builtin_amdgcn_mfma_f32_16x16x32_f16(A10, b0, c1, 0, 0, 0);
            c1 = __builtin_amdgcn_mfma_f32_16x16x32_f16(A11, b1, c1, 0, 0, 0);
#pragma unroll
            for (int r = 0; r < 4; ++r) {
                act[m0 + q * 4 + r][nt * 16 + fm]      = (f16)c0[r];
                act[m0 + 16 + q * 4 + r][nt * 16 + fm] = (f16)c1[r];
            }
        }
        // wave-private reshuffle -> 16B stores
#pragma unroll
        for (int it = 0; it < 4; ++it) {
            int row = (lane >> 3) + it * 8;      // 0..31
            int er = e0 + m0 + row;
            if (er < E) {
                int p = pos[er];
                half8_t v = *(const half8_t*)&act[m0 + row][(lane & 7) * 8];
                *(half8_t*)&mixp[(size_t)p * 256 + l * 64 + (lane & 7) * 8] = v;
            }
        }
    };

    __syncthreads();   // everyone done reading wB/wC
    {
        int n = t & 63;
        int k0 = t >> 6;
        for (int k = k0; k < 64; k += 4) {
            wB[n][k] = (f16)w4[k * 256 + n];           // l=0
            wC[n][k] = (f16)w4[k * 256 + 64 + n];      // l=1
        }
    }
    __syncthreads();
    do_l(0, wB);
    do_l(1, wC);
    __syncthreads();
    {
        int n = t & 63;
        int k0 = t >> 6;
        for (int k = k0; k < 64; k += 4) {
            wB[n][k] = (f16)w4[k * 256 + 128 + n];     // l=2
            wC[n][k] = (f16)w4[k * 256 + 192 + n];     // l=3
        }
    }
    __syncthreads();
    do_l(2, wB);
    do_l(3, wC);
}

// ---------------- K2: streaming per-node gather + fused down-proj ----------------
// wave = node, lane = channel. All per-edge streams (sndp, yb, mixp) are in
// CSR order -> sequential reads; only x rows are random (L2-resident 2.5MB).
__global__ __launch_bounds__(256) void k_gather(const float* __restrict__ x,
        const f16* __restrict__ mixp, const float* __restrict__ yb,
        const int* __restrict__ sndp, const int* __restrict__ off,
        const float* __restrict__ Wd, float* __restrict__ out, int N) {
    __shared__ float sbuf[4][1024];
    int wv = threadIdx.x >> 6;
    int lane = threadIdx.x & 63;
    int n = blockIdx.x * 4 + wv;
    if (n >= N) return;

    float o[16];
#pragma unroll
    for (int i = 0; i < 16; ++i) o[i] = 0.f;

    auto process = [&](int i) {
        int s = sndp[i];
        const float* yr = yb + (size_t)i * 16;
        float4 A = *(const float4*)(yr + 0);
        float4 B = *(const float4*)(yr + 4);
        float4 Cv = *(const float4*)(yr + 8);
        float4 D = *(const float4*)(yr + 12);
        float sf = x[(size_t)s * 64 + lane];
        const f16* mr = mixp + (size_t)i * 256;
        float t0 = sf * (float)mr[lane];
        float t1 = sf * (float)mr[64 + lane];
        float t2 = sf * (float)mr[128 + lane];
        float t3 = sf * (float)mr[192 + lane];
        o[0]  += t0;
        o[1]  += t1 * A.y;
        o[2]  += t1 * A.z;
        o[3]  += t1 * A.w;
        o[4]  += t2 * B.x;
        o[5]  += t2 * B.y;
        o[6]  += t2 * B.z;
        o[7]  += t2 * B.w;
        o[8]  += t2 * Cv.x;
        o[9]  += t3 * Cv.y;
        o[10] += t3 * Cv.z;
        o[11] += t3 * Cv.w;
        o[12] += t3 * D.x;
        o[13] += t3 * D.y;
        o[14] += t3 * D.z;
        o[15] += t3 * D.w;
    };

    int beg = off[n], end = off[n + 1];
    int i = beg;
    for (; i + 1 < end; i += 2) { process(i); process(i + 1); }
    if (i < end) process(i);

    // register -> LDS transpose (wave-private region, no barrier needed)
#pragma unroll
    for (int t = 0; t < 16; ++t) sbuf[wv][t * 64 + lane] = o[t];

    float d[16];
#pragma unroll
    for (int i2 = 0; i2 < 16; ++i2) d[i2] = 0.f;
#pragma unroll 1
    for (int c = 0; c < 64; ++c) {
        float w0 = Wd[c * 64 + lane];
        float w1r = Wd[4096 + c * 64 + lane];
        float w2r = Wd[8192 + c * 64 + lane];
        float w3r = Wd[12288 + c * 64 + lane];
        const float* sb = &sbuf[wv][c];
        d[0] += sb[0] * w0;
#pragma unroll
        for (int m = 0; m < 3; ++m) d[1 + m] += sb[(1 + m) * 64] * w1r;
#pragma unroll
        for (int m = 0; m < 5; ++m) d[4 + m] += sb[(4 + m) * 64] * w2r;
#pragma unroll
        for (int m = 0; m < 7; ++m) d[9 + m] += sb[(9 + m) * 64] * w3r;
    }

    float* outr = out + (size_t)n * 1024;
    outr[lane] = 0.25f * d[0];
#pragma unroll
    for (int m = 0; m < 3; ++m) outr[64 + lane * 3 + m] = 0.25f * d[1 + m];
#pragma unroll
    for (int m = 0; m < 5; ++m) outr[256 + lane * 5 + m] = 0.25f * d[4 + m];
#pragma unroll
    for (int m = 0; m < 7; ++m) outr[576 + lane * 7 + m] = 0.25f * d[9 + m];
}

extern "C" void kernel_launch(void* const* d_in, const int* in_sizes, int n_in,
                              void* d_out, int out_size, void* d_ws, size_t ws_size,
                              hipStream_t stream) {
    const float* vectors    = (const float*)d_in[0];
    const float* node_feats = (const float*)d_in[1];
    const float* radial     = (const float*)d_in[2];
    const float* W_up       = (const float*)d_in[3];
    const float* w1         = (const float*)d_in[4];
    const float* w2         = (const float*)d_in[5];
    const float* w3         = (const float*)d_in[6];
    const float* w4         = (const float*)d_in[7];
    const float* Wd         = (const float*)d_in[8];
    const int*   snd        = (const int*)d_in[9];
    const int*   rcv        = (const int*)d_in[10];
    float* out = (float*)d_out;

    int E = in_sizes[9];
    int N = in_sizes[1] / CC;

    // ws: x [N*64]f | yb [E*16]f | mixp [E*256]f16 | cnt,off,cur [N..]i | eid,pos,sndp [E]i
    float* ws   = (float*)d_ws;
    float* x    = ws;
    float* yb   = x + (size_t)N * 64;
    f16*   mixp = (f16*)(yb + (size_t)E * 16);
    int*   cnt  = (int*)((char*)mixp + (size_t)E * 256 * sizeof(f16));
    int*   off  = cnt + N;
    int*   cur  = off + (N + 1);
    int*   eid  = cur + N;
    int*   pos  = eid + E;
    int*   sndp = pos + E;

    hipMemsetAsync(cnt, 0, (size_t)N * sizeof(int), stream);

    k_up<<<(N * CC + 255) / 256, 256, 0, stream>>>(node_feats, W_up, x, N);
    k_hist<<<(E + 255) / 256, 256, 0, stream>>>(rcv, cnt, E);
    k_scan<<<1, 1024, 0, stream>>>(cnt, off, cur, N);
    k_fill<<<(E + 255) / 256, 256, 0, stream>>>(rcv, snd, cur, eid, pos, sndp, E);
    k_sph<<<(E + 255) / 256, 256, 0, stream>>>(eid, vectors, yb, E);
    k_mlp<<<(E + 127) / 128, 256, 0, stream>>>(radial, w1, w2, w3, w4, pos, mixp, E);
    k_gather<<<(N + 3) / 4, 256, 0, stream>>>(x, mixp, yb, sndp, off, Wd, out, N);
}